// Round 1
// baseline (1005.166 us; speedup 1.0000x reference)
//
#include <hip/hip_runtime.h>
#include <math.h>

// Problem dims
#define Bb 2
#define Tt 16
#define Hh 64
#define Ww 64
#define Cc 64
// Element strides in (B,T,H,W,C) layout
#define ST_ (Hh*Ww*Cc)    // 262144
#define SH_ (Ww*Cc)       // 4096
#define SB_ (Tt*Hh*Ww*Cc) // 4194304

#define TWO_PI 6.2831853071795864769f

// ---------------------------------------------------------------------------
// Pass 1: forward DFT along W, real input -> complex. One wg per (b,t,h).
// ---------------------------------------------------------------------------
__global__ __launch_bounds__(256) void k_fft_w_fwd(const float* __restrict__ x,
                                                   float2* __restrict__ X) {
    __shared__ float xs[64 * 64];   // [w][c]
    __shared__ float2 tw[64];
    int tid = threadIdx.x;
    int base = blockIdx.x * 4096;   // (b,t,h) flattened * W*C
    for (int k = 0; k < 16; ++k) {
        int idx = tid + k * 256;
        xs[idx] = x[base + idx];
    }
    if (tid < 64) {
        float ang = -TWO_PI * (float)tid / 64.0f;
        tw[tid] = make_float2(cosf(ang), sinf(ang));
    }
    __syncthreads();
    int c = tid & 63;
    for (int wp = tid >> 6; wp < 64; wp += 4) {
        float re = 0.f, im = 0.f;
        for (int w = 0; w < 64; ++w) {
            float v = xs[w * 64 + c];
            float2 t = tw[(w * wp) & 63];
            re = fmaf(v, t.x, re);
            im = fmaf(v, t.y, im);
        }
        X[base + wp * 64 + c] = make_float2(re, im);
    }
}

// ---------------------------------------------------------------------------
// DFT along H, complex in-place. One wg per (b,t,w). SIGN=-1 fwd, +1 inv.
// ---------------------------------------------------------------------------
template <int SIGN>
__global__ __launch_bounds__(256) void k_fft_h(float2* __restrict__ X) {
    __shared__ float2 xs[64 * 64];  // [h][c] 32KB
    __shared__ float2 tw[64];
    int tid = threadIdx.x;
    int s = blockIdx.x;
    int bt = s >> 6, w = s & 63;
    int base = bt * ST_ + w * 64;
    for (int k = 0; k < 16; ++k) {
        int idx = tid + k * 256;
        int h = idx >> 6, c = idx & 63;
        xs[idx] = X[base + h * SH_ + c];
    }
    if (tid < 64) {
        float ang = (float)SIGN * TWO_PI * (float)tid / 64.0f;
        tw[tid] = make_float2(cosf(ang), sinf(ang));
    }
    __syncthreads();
    int c = tid & 63;
    for (int hp = tid >> 6; hp < 64; hp += 4) {
        float re = 0.f, im = 0.f;
        for (int h = 0; h < 64; ++h) {
            float2 v = xs[h * 64 + c];
            float2 t = tw[(h * hp) & 63];
            re = fmaf(v.x, t.x, re);
            re = fmaf(-v.y, t.y, re);
            im = fmaf(v.x, t.y, im);
            im = fmaf(v.y, t.x, im);
        }
        X[base + hp * SH_ + c] = make_float2(re, im);
    }
}

// ---------------------------------------------------------------------------
// DFT along T, complex in-place. One wg per (b,h,w).
// ---------------------------------------------------------------------------
template <int SIGN>
__global__ __launch_bounds__(256) void k_fft_t(float2* __restrict__ X) {
    __shared__ float2 xs[16 * 64];  // [t][c] 8KB
    __shared__ float2 tw[16];
    int tid = threadIdx.x;
    int s = blockIdx.x;
    int b = s >> 12, hw = s & 4095;
    int base = b * SB_ + hw * 64;
    for (int k = 0; k < 4; ++k) {
        int idx = tid + k * 256;
        int t = idx >> 6, c = idx & 63;
        xs[idx] = X[base + t * ST_ + c];
    }
    if (tid < 16) {
        float ang = (float)SIGN * TWO_PI * (float)tid / 16.0f;
        tw[tid] = make_float2(cosf(ang), sinf(ang));
    }
    __syncthreads();
    int c = tid & 63;
    for (int tp = tid >> 6; tp < 16; tp += 4) {
        float re = 0.f, im = 0.f;
        for (int t = 0; t < 16; ++t) {
            float2 v = xs[t * 64 + c];
            float2 tww = tw[(t * tp) & 15];
            re = fmaf(v.x, tww.x, re);
            re = fmaf(-v.y, tww.y, re);
            im = fmaf(v.x, tww.y, im);
            im = fmaf(v.y, tww.x, im);
        }
        X[base + tp * ST_ + c] = make_float2(re, im);
    }
}

// ---------------------------------------------------------------------------
// Gating + 16-step scan along T, in-place on X. 256 thr = 4 sites x 64 chan.
// A_f/B_f recomputed from the 27 kernel taps (no FFT of kernels needed):
//   A_f[t,h,w,c] = sum_taps K[c,kt,kh,kw] e^{-2pi i (t(kt-1)/16 + h(kh-1)/64 + w(kw-1)/64)}
// ---------------------------------------------------------------------------
__global__ __launch_bounds__(256) void k_scan(
    const float* __restrict__ x, float2* __restrict__ X,
    const float* __restrict__ Ak, const float* __restrict__ Bk,
    const float* __restrict__ fb, const float* __restrict__ fs,
    const float* __restrict__ ib, const float* __restrict__ isc_,
    const float* __restrict__ dW, const float* __restrict__ db) {
    __shared__ float Wd[64 * 64];     // delta_W, 16KB  [d_in][c_out]
    __shared__ float xr[4][16][64];   // x rows per site, 16KB
    int tid = threadIdx.x;
    for (int k = 0; k < 16; ++k) Wd[tid + k * 256] = dW[tid + k * 256];
    int g = tid >> 6, c = tid & 63;
    int site = blockIdx.x * 4 + g;
    int b = site >> 12, hw = site & 4095;
    int h = hw >> 6, w = hw & 63;
    int base = b * SB_ + hw * 64;
    for (int t = 0; t < 16; ++t)
        xr[g][t][c] = x[base + t * ST_ + c];
    __syncthreads();

    // per-axis twiddles for the 3 taps: e[k] = e^{-2pi i coord (k-1)/N}
    float sh, ch; sincosf(TWO_PI * (float)h / 64.0f, &sh, &ch);
    float sw, cw; sincosf(TWO_PI * (float)w / 64.0f, &sw, &cw);
    float2 eh[3] = { make_float2(ch, sh), make_float2(1.f, 0.f), make_float2(ch, -sh) };
    float2 ew[3] = { make_float2(cw, sw), make_float2(1.f, 0.f), make_float2(cw, -sw) };
    // G[kt] = sum_{kh,kw} eh*ew*K  (complex, K real)
    float2 GA[3], GB[3];
    for (int kt = 0; kt < 3; ++kt) { GA[kt] = make_float2(0.f, 0.f); GB[kt] = make_float2(0.f, 0.f); }
    for (int kh = 0; kh < 3; ++kh) {
        for (int kw = 0; kw < 3; ++kw) {
            float2 e;
            e.x = eh[kh].x * ew[kw].x - eh[kh].y * ew[kw].y;
            e.y = eh[kh].x * ew[kw].y + eh[kh].y * ew[kw].x;
            for (int kt = 0; kt < 3; ++kt) {
                float ka = Ak[((c * 3 + kt) * 3 + kh) * 3 + kw];
                float kb = Bk[((c * 3 + kt) * 3 + kh) * 3 + kw];
                GA[kt].x = fmaf(ka, e.x, GA[kt].x);
                GA[kt].y = fmaf(ka, e.y, GA[kt].y);
                GB[kt].x = fmaf(kb, e.x, GB[kt].x);
                GB[kt].y = fmaf(kb, e.y, GB[kt].y);
            }
        }
    }
    float fbc = fb[c], fsc = fs[c], ibc = ib[c], iscv = isc_[c], dbc = db[c];

    float2 hv = make_float2(0.f, 0.f);
    for (int t = 0; t < 16; ++t) {
        float st, ct; sincosf(TWO_PI * (float)t / 16.0f, &st, &ct);
        // A_f = e_t0*G0 + G1 + e_t2*G2 with e_t0=(ct,st), e_t2=(ct,-st)
        float2 Af, Bf;
        Af.x = GA[1].x + ct * (GA[0].x + GA[2].x) - st * (GA[0].y - GA[2].y);
        Af.y = GA[1].y + ct * (GA[0].y + GA[2].y) + st * (GA[0].x - GA[2].x);
        Bf.x = GB[1].x + ct * (GB[0].x + GB[2].x) - st * (GB[0].y - GB[2].y);
        Bf.y = GB[1].y + ct * (GB[0].y + GB[2].y) + st * (GB[0].x - GB[2].x);

        float xc = xr[g][t][c];
        float fg = 1.f / (1.f + expf(-(fbc + fsc * xc)));
        float igv = 1.f / (1.f + expf(-(ibc + iscv * xc)));
        float dot = dbc;
        for (int d = 0; d < 64; ++d)
            dot = fmaf(xr[g][t][d], Wd[d * 64 + c], dot);
        float delta = (dot > 20.f) ? dot : log1pf(expf(dot));

        float2 Xv = X[base + t * ST_ + c];
        float sR = igv * delta;
        float2 bbv;
        bbv.x = sR * (Bf.x * Xv.x - Bf.y * Xv.y);
        bbv.y = sR * (Bf.x * Xv.y + Bf.y * Xv.x);
        float2 av = make_float2(fg * Af.x, fg * Af.y);
        float2 nh;
        nh.x = av.x * hv.x - av.y * hv.y + bbv.x;
        nh.y = av.x * hv.y + av.y * hv.x + bbv.y;
        hv = nh;
        X[base + t * ST_ + c] = hv;
    }
}

// ---------------------------------------------------------------------------
// Final pass: inverse DFT along W, write real part * 1/65536 to out.
// ---------------------------------------------------------------------------
__global__ __launch_bounds__(256) void k_fft_w_inv_out(const float2* __restrict__ X,
                                                       float* __restrict__ out) {
    __shared__ float2 xs[64 * 64];  // 32KB
    __shared__ float2 tw[64];
    int tid = threadIdx.x;
    int base = blockIdx.x * 4096;
    for (int k = 0; k < 16; ++k) {
        int idx = tid + k * 256;
        xs[idx] = X[base + idx];
    }
    if (tid < 64) {
        float ang = TWO_PI * (float)tid / 64.0f;
        tw[tid] = make_float2(cosf(ang), sinf(ang));
    }
    __syncthreads();
    int c = tid & 63;
    for (int wp = tid >> 6; wp < 64; wp += 4) {
        float re = 0.f;
        for (int w = 0; w < 64; ++w) {
            float2 v = xs[w * 64 + c];
            float2 t = tw[(w * wp) & 63];
            re = fmaf(v.x, t.x, re);
            re = fmaf(-v.y, t.y, re);
        }
        out[base + wp * 64 + c] = re * (1.0f / 65536.0f);
    }
}

extern "C" void kernel_launch(void* const* d_in, const int* in_sizes, int n_in,
                              void* d_out, int out_size, void* d_ws, size_t ws_size,
                              hipStream_t stream) {
    const float* x   = (const float*)d_in[0];
    const float* Ak  = (const float*)d_in[1];
    const float* Bk  = (const float*)d_in[2];
    const float* fb  = (const float*)d_in[3];
    const float* fs  = (const float*)d_in[4];
    const float* ib  = (const float*)d_in[5];
    const float* is_ = (const float*)d_in[6];
    const float* dW  = (const float*)d_in[7];
    const float* db  = (const float*)d_in[8];
    float* out = (float*)d_out;
    float2* X = (float2*)d_ws;  // (B,T,H,W,C) complex fp32 = 64 MiB

    // Forward FFT over (W, H, T)
    k_fft_w_fwd<<<Bb * Tt * Hh, 256, 0, stream>>>(x, X);
    k_fft_h<-1><<<Bb * Tt * Ww, 256, 0, stream>>>(X);
    k_fft_t<-1><<<Bb * Hh * Ww, 256, 0, stream>>>(X);
    // Gates + A_f/B_f + 16-step scan (in place)
    k_scan<<<(Bb * Hh * Ww) / 4, 256, 0, stream>>>(x, X, Ak, Bk, fb, fs, ib, is_, dW, db);
    // Inverse FFT over (T, H, W), final pass emits scaled real part
    k_fft_t<1><<<Bb * Hh * Ww, 256, 0, stream>>>(X);
    k_fft_h<1><<<Bb * Tt * Ww, 256, 0, stream>>>(X);
    k_fft_w_inv_out<<<Bb * Tt * Hh, 256, 0, stream>>>(X, out);
}

// Round 2
// 288.926 us; speedup vs baseline: 3.4790x; 3.4790x over previous
//
#include <hip/hip_runtime.h>
#include <math.h>

// Problem dims
#define Bb 2
#define Tt 16
#define Hh 64
#define Ww 64
#define Cc 64
#define ST_ (Hh*Ww*Cc)    // 262144
#define SH_ (Ww*Cc)       // 4096
#define SB_ (Tt*Hh*Ww*Cc) // 4194304

#define TWO_PI 6.2831853071795864769f

__device__ __forceinline__ float2 cmul(float2 a, float2 b) {
    return make_float2(fmaf(a.x, b.x, -a.y * b.y), fmaf(a.x, b.y, a.y * b.x));
}
__device__ __forceinline__ float2 cadd(float2 a, float2 b) { return make_float2(a.x + b.x, a.y + b.y); }
__device__ __forceinline__ float2 csub(float2 a, float2 b) { return make_float2(a.x - b.x, a.y - b.y); }

// 8-pt DIF FFT in-place; output in computed (bit-reversed) order:
// v[m] = X[brev3(m)] where X[k] = sum_n v_in[n] e^{S*2pi i nk/8}.
// brev3 = {0,4,2,6,1,5,3,7}. Verified: delta-at-n=1 input gives W8^{S k}.
template <int S>
__device__ __forceinline__ void fft8(float2 v[8]) {
    const float R = 0.70710678118654752f;
    float2 s0 = cadd(v[0], v[4]), d0 = csub(v[0], v[4]);
    float2 s1 = cadd(v[1], v[5]), d1 = csub(v[1], v[5]);
    float2 s2 = cadd(v[2], v[6]), d2 = csub(v[2], v[6]);
    float2 s3 = cadd(v[3], v[7]), d3 = csub(v[3], v[7]);
    d1 = make_float2(R * (d1.x - (float)S * d1.y), R * ((float)S * d1.x + d1.y));
    { float2 t = d2; d2 = make_float2(-(float)S * t.y, (float)S * t.x); }
    d3 = make_float2(R * (-d3.x - (float)S * d3.y), R * ((float)S * d3.x - d3.y));
    // even fft4 -> X0,X4,X2,X6
    float2 u0 = cadd(s0, s2), u2 = csub(s0, s2);
    float2 u1 = cadd(s1, s3), u3t = csub(s1, s3);
    float2 u3 = make_float2(-(float)S * u3t.y, (float)S * u3t.x);
    v[0] = cadd(u0, u1); v[1] = csub(u0, u1); v[2] = cadd(u2, u3); v[3] = csub(u2, u3);
    // odd fft4 -> X1,X5,X3,X7
    float2 w0 = cadd(d0, d2), w2 = csub(d0, d2);
    float2 w1 = cadd(d1, d3), w3t = csub(d1, d3);
    float2 w3 = make_float2(-(float)S * w3t.y, (float)S * w3t.x);
    v[4] = cadd(w0, w1); v[5] = csub(w0, w1); v[6] = cadd(w2, w3); v[7] = csub(w2, w3);
}

// ---------------------------------------------------------------------------
// Radix-8x8 64-pt FFT along W, real input -> complex. One wg per (b,t,h).
// Thread (j,cl): slot j of lines c=cl and c=cl+32. One LDS transpose.
// ---------------------------------------------------------------------------
__global__ __launch_bounds__(256) void k_fft_w_fwd(const float* __restrict__ x,
                                                   float2* __restrict__ X) {
    __shared__ float2 ex[64 * 65];  // [line][65] pad breaks bank alignment
    const int brev[8] = {0, 4, 2, 6, 1, 5, 3, 7};
    int tid = threadIdx.x;
    int j = tid >> 5, cl = tid & 31;
    int base = blockIdx.x * 4096;
    float2 v[2][8];
#pragma unroll
    for (int q = 0; q < 2; ++q) {
        int c = cl + 32 * q;
#pragma unroll
        for (int n1 = 0; n1 < 8; ++n1)
            v[q][n1] = make_float2(x[base + (8 * n1 + j) * 64 + c], 0.f);
    }
    float sj, cj; sincosf(-TWO_PI * (float)j / 64.f, &sj, &cj);
    float2 w1 = make_float2(cj, sj);
#pragma unroll
    for (int q = 0; q < 2; ++q) {
        fft8<-1>(v[q]);
        int c = cl + 32 * q;
        float2 tw = make_float2(1.f, 0.f);
#pragma unroll
        for (int k0 = 0; k0 < 8; ++k0) {        // natural-order k0
            ex[c * 65 + j * 8 + k0] = cmul(v[q][brev[k0]], tw);
            tw = cmul(tw, w1);
        }
    }
    __syncthreads();
#pragma unroll
    for (int q = 0; q < 2; ++q) {
        int c = cl + 32 * q;
        float2 z[8];
#pragma unroll
        for (int n0 = 0; n0 < 8; ++n0) z[n0] = ex[c * 65 + n0 * 8 + j];
        fft8<-1>(z);
#pragma unroll
        for (int m = 0; m < 8; ++m)
            X[base + (j + 8 * brev[m]) * 64 + c] = z[m];
    }
}

// ---------------------------------------------------------------------------
// Radix-8x8 64-pt FFT along H, complex in-place. One wg per (b,t,w).
// ---------------------------------------------------------------------------
template <int S>
__global__ __launch_bounds__(256) void k_fft_h(float2* __restrict__ X) {
    __shared__ float2 ex[64 * 65];
    const int brev[8] = {0, 4, 2, 6, 1, 5, 3, 7};
    int tid = threadIdx.x;
    int j = tid >> 5, cl = tid & 31;
    int s = blockIdx.x;
    int bt = s >> 6, w = s & 63;
    int base = bt * ST_ + w * 64;
    float2 v[2][8];
#pragma unroll
    for (int q = 0; q < 2; ++q) {
        int c = cl + 32 * q;
#pragma unroll
        for (int n1 = 0; n1 < 8; ++n1)
            v[q][n1] = X[base + (8 * n1 + j) * SH_ + c];
    }
    float sj, cj; sincosf((float)S * TWO_PI * (float)j / 64.f, &sj, &cj);
    float2 w1 = make_float2(cj, sj);
#pragma unroll
    for (int q = 0; q < 2; ++q) {
        fft8<S>(v[q]);
        int c = cl + 32 * q;
        float2 tw = make_float2(1.f, 0.f);
#pragma unroll
        for (int k0 = 0; k0 < 8; ++k0) {
            ex[c * 65 + j * 8 + k0] = cmul(v[q][brev[k0]], tw);
            tw = cmul(tw, w1);
        }
    }
    __syncthreads();
#pragma unroll
    for (int q = 0; q < 2; ++q) {
        int c = cl + 32 * q;
        float2 z[8];
#pragma unroll
        for (int n0 = 0; n0 < 8; ++n0) z[n0] = ex[c * 65 + n0 * 8 + j];
        fft8<S>(z);
#pragma unroll
        for (int m = 0; m < 8; ++m)
            X[base + (j + 8 * brev[m]) * SH_ + c] = z[m];
    }
}

// ---------------------------------------------------------------------------
// DFT along T (16-pt, cheap), complex in-place. One wg per (b,h,w).
// ---------------------------------------------------------------------------
template <int SIGN>
__global__ __launch_bounds__(256) void k_fft_t(float2* __restrict__ X) {
    __shared__ float2 xs[16 * 64];
    __shared__ float2 tw[16];
    int tid = threadIdx.x;
    int s = blockIdx.x;
    int b = s >> 12, hw = s & 4095;
    int base = b * SB_ + hw * 64;
    for (int k = 0; k < 4; ++k) {
        int idx = tid + k * 256;
        int t = idx >> 6, c = idx & 63;
        xs[idx] = X[base + t * ST_ + c];
    }
    if (tid < 16) {
        float ang = (float)SIGN * TWO_PI * (float)tid / 16.0f;
        tw[tid] = make_float2(cosf(ang), sinf(ang));
    }
    __syncthreads();
    int c = tid & 63;
    for (int tp = tid >> 6; tp < 16; tp += 4) {
        float re = 0.f, im = 0.f;
        for (int t = 0; t < 16; ++t) {
            float2 v = xs[t * 64 + c];
            float2 tww = tw[(t * tp) & 15];
            re = fmaf(v.x, tww.x, re);
            re = fmaf(-v.y, tww.y, re);
            im = fmaf(v.x, tww.y, im);
            im = fmaf(v.y, tww.x, im);
        }
        X[base + tp * ST_ + c] = make_float2(re, im);
    }
}

// ---------------------------------------------------------------------------
// Gating + 16-step scan along T, in-place on X. 256 thr = 4 sites x 64 chan.
// ---------------------------------------------------------------------------
__global__ __launch_bounds__(256) void k_scan(
    const float* __restrict__ x, float2* __restrict__ X,
    const float* __restrict__ Ak, const float* __restrict__ Bk,
    const float* __restrict__ fb, const float* __restrict__ fs,
    const float* __restrict__ ib, const float* __restrict__ isc_,
    const float* __restrict__ dW, const float* __restrict__ db) {
    __shared__ float Wd[64 * 64];
    __shared__ float xr[4][16][64];
    int tid = threadIdx.x;
    for (int k = 0; k < 16; ++k) Wd[tid + k * 256] = dW[tid + k * 256];
    int g = tid >> 6, c = tid & 63;
    int site = blockIdx.x * 4 + g;
    int b = site >> 12, hw = site & 4095;
    int h = hw >> 6, w = hw & 63;
    int base = b * SB_ + hw * 64;
    for (int t = 0; t < 16; ++t)
        xr[g][t][c] = x[base + t * ST_ + c];
    __syncthreads();

    float sh, ch; sincosf(TWO_PI * (float)h / 64.0f, &sh, &ch);
    float sw, cw; sincosf(TWO_PI * (float)w / 64.0f, &sw, &cw);
    float2 eh[3] = { make_float2(ch, sh), make_float2(1.f, 0.f), make_float2(ch, -sh) };
    float2 ew[3] = { make_float2(cw, sw), make_float2(1.f, 0.f), make_float2(cw, -sw) };
    float2 GA[3], GB[3];
    for (int kt = 0; kt < 3; ++kt) { GA[kt] = make_float2(0.f, 0.f); GB[kt] = make_float2(0.f, 0.f); }
    for (int kh = 0; kh < 3; ++kh) {
        for (int kw = 0; kw < 3; ++kw) {
            float2 e;
            e.x = eh[kh].x * ew[kw].x - eh[kh].y * ew[kw].y;
            e.y = eh[kh].x * ew[kw].y + eh[kh].y * ew[kw].x;
            for (int kt = 0; kt < 3; ++kt) {
                float ka = Ak[((c * 3 + kt) * 3 + kh) * 3 + kw];
                float kb = Bk[((c * 3 + kt) * 3 + kh) * 3 + kw];
                GA[kt].x = fmaf(ka, e.x, GA[kt].x);
                GA[kt].y = fmaf(ka, e.y, GA[kt].y);
                GB[kt].x = fmaf(kb, e.x, GB[kt].x);
                GB[kt].y = fmaf(kb, e.y, GB[kt].y);
            }
        }
    }
    float fbc = fb[c], fsc = fs[c], ibc = ib[c], iscv = isc_[c], dbc = db[c];

    float2 hv = make_float2(0.f, 0.f);
    for (int t = 0; t < 16; ++t) {
        float st, ct; sincosf(TWO_PI * (float)t / 16.0f, &st, &ct);
        float2 Af, Bf;
        Af.x = GA[1].x + ct * (GA[0].x + GA[2].x) - st * (GA[0].y - GA[2].y);
        Af.y = GA[1].y + ct * (GA[0].y + GA[2].y) + st * (GA[0].x - GA[2].x);
        Bf.x = GB[1].x + ct * (GB[0].x + GB[2].x) - st * (GB[0].y - GB[2].y);
        Bf.y = GB[1].y + ct * (GB[0].y + GB[2].y) + st * (GB[0].x - GB[2].x);

        float xc = xr[g][t][c];
        float fg = 1.f / (1.f + expf(-(fbc + fsc * xc)));
        float igv = 1.f / (1.f + expf(-(ibc + iscv * xc)));
        float dot = dbc;
        for (int d = 0; d < 64; ++d)
            dot = fmaf(xr[g][t][d], Wd[d * 64 + c], dot);
        float delta = (dot > 20.f) ? dot : log1pf(expf(dot));

        float2 Xv = X[base + t * ST_ + c];
        float sR = igv * delta;
        float2 bbv;
        bbv.x = sR * (Bf.x * Xv.x - Bf.y * Xv.y);
        bbv.y = sR * (Bf.x * Xv.y + Bf.y * Xv.x);
        float2 av = make_float2(fg * Af.x, fg * Af.y);
        float2 nh;
        nh.x = av.x * hv.x - av.y * hv.y + bbv.x;
        nh.y = av.x * hv.y + av.y * hv.x + bbv.y;
        hv = nh;
        X[base + t * ST_ + c] = hv;
    }
}

// ---------------------------------------------------------------------------
// Radix-8x8 inverse 64-pt FFT along W + real output * 1/65536.
// ---------------------------------------------------------------------------
__global__ __launch_bounds__(256) void k_fft_w_inv_out(const float2* __restrict__ X,
                                                       float* __restrict__ out) {
    __shared__ float2 ex[64 * 65];
    const int brev[8] = {0, 4, 2, 6, 1, 5, 3, 7};
    int tid = threadIdx.x;
    int j = tid >> 5, cl = tid & 31;
    int base = blockIdx.x * 4096;
    float2 v[2][8];
#pragma unroll
    for (int q = 0; q < 2; ++q) {
        int c = cl + 32 * q;
#pragma unroll
        for (int n1 = 0; n1 < 8; ++n1)
            v[q][n1] = X[base + (8 * n1 + j) * 64 + c];
    }
    float sj, cj; sincosf(TWO_PI * (float)j / 64.f, &sj, &cj);
    float2 w1 = make_float2(cj, sj);
#pragma unroll
    for (int q = 0; q < 2; ++q) {
        fft8<1>(v[q]);
        int c = cl + 32 * q;
        float2 tw = make_float2(1.f, 0.f);
#pragma unroll
        for (int k0 = 0; k0 < 8; ++k0) {
            ex[c * 65 + j * 8 + k0] = cmul(v[q][brev[k0]], tw);
            tw = cmul(tw, w1);
        }
    }
    __syncthreads();
#pragma unroll
    for (int q = 0; q < 2; ++q) {
        int c = cl + 32 * q;
        float2 z[8];
#pragma unroll
        for (int n0 = 0; n0 < 8; ++n0) z[n0] = ex[c * 65 + n0 * 8 + j];
        fft8<1>(z);
#pragma unroll
        for (int m = 0; m < 8; ++m)
            out[base + (j + 8 * brev[m]) * 64 + c] = z[m].x * (1.0f / 65536.0f);
    }
}

extern "C" void kernel_launch(void* const* d_in, const int* in_sizes, int n_in,
                              void* d_out, int out_size, void* d_ws, size_t ws_size,
                              hipStream_t stream) {
    const float* x   = (const float*)d_in[0];
    const float* Ak  = (const float*)d_in[1];
    const float* Bk  = (const float*)d_in[2];
    const float* fb  = (const float*)d_in[3];
    const float* fs  = (const float*)d_in[4];
    const float* ib  = (const float*)d_in[5];
    const float* is_ = (const float*)d_in[6];
    const float* dW  = (const float*)d_in[7];
    const float* db  = (const float*)d_in[8];
    float* out = (float*)d_out;
    float2* X = (float2*)d_ws;  // (B,T,H,W,C) complex fp32 = 64 MiB

    k_fft_w_fwd<<<Bb * Tt * Hh, 256, 0, stream>>>(x, X);
    k_fft_h<-1><<<Bb * Tt * Ww, 256, 0, stream>>>(X);
    k_fft_t<-1><<<Bb * Hh * Ww, 256, 0, stream>>>(X);
    k_scan<<<(Bb * Hh * Ww) / 4, 256, 0, stream>>>(x, X, Ak, Bk, fb, fs, ib, is_, dW, db);
    k_fft_t<1><<<Bb * Hh * Ww, 256, 0, stream>>>(X);
    k_fft_h<1><<<Bb * Tt * Ww, 256, 0, stream>>>(X);
    k_fft_w_inv_out<<<Bb * Tt * Hh, 256, 0, stream>>>(X, out);
}

// Round 4
// 245.690 us; speedup vs baseline: 4.0912x; 1.1760x over previous
//
#include <hip/hip_runtime.h>
#include <math.h>

// Problem dims
#define Bb 2
#define Tt 16
#define Hh 64
#define Ww 64
#define Cc 64
#define ST_ (Hh*Ww*Cc)    // 262144
#define SH_ (Ww*Cc)       // 4096
#define SB_ (Tt*Hh*Ww*Cc) // 4194304

#define TWO_PI 6.2831853071795864769f

__device__ __forceinline__ float2 cmul(float2 a, float2 b) {
    return make_float2(fmaf(a.x, b.x, -a.y * b.y), fmaf(a.x, b.y, a.y * b.x));
}
__device__ __forceinline__ float2 cadd(float2 a, float2 b) { return make_float2(a.x + b.x, a.y + b.y); }
__device__ __forceinline__ float2 csub(float2 a, float2 b) { return make_float2(a.x - b.x, a.y - b.y); }

// bf16 pair pack/unpack (re low 16, im high 16). RNE rounding; range = fp32.
__device__ __forceinline__ unsigned bfpack(float2 f) {
    unsigned r = __float_as_uint(f.x);
    unsigned i = __float_as_uint(f.y);
    r = (r + 0x7fffu + ((r >> 16) & 1u)) >> 16;
    i = (i + 0x7fffu + ((i >> 16) & 1u)) >> 16;
    return r | (i << 16);
}
__device__ __forceinline__ float2 bfunpack(unsigned u) {
    return make_float2(__uint_as_float(u << 16), __uint_as_float(u & 0xffff0000u));
}

// ---------------------------------------------------------------------------
// 8-pt DIF FFT in-place; output order brev3={0,4,2,6,1,5,3,7}
// ---------------------------------------------------------------------------
template <int S>
__device__ __forceinline__ void fft8(float2 v[8]) {
    const float R = 0.70710678118654752f;
    float2 s0 = cadd(v[0], v[4]), d0 = csub(v[0], v[4]);
    float2 s1 = cadd(v[1], v[5]), d1 = csub(v[1], v[5]);
    float2 s2 = cadd(v[2], v[6]), d2 = csub(v[2], v[6]);
    float2 s3 = cadd(v[3], v[7]), d3 = csub(v[3], v[7]);
    d1 = make_float2(R * (d1.x - (float)S * d1.y), R * ((float)S * d1.x + d1.y));
    { float2 t = d2; d2 = make_float2(-(float)S * t.y, (float)S * t.x); }
    d3 = make_float2(R * (-d3.x - (float)S * d3.y), R * ((float)S * d3.x - d3.y));
    float2 u0 = cadd(s0, s2), u2 = csub(s0, s2);
    float2 u1 = cadd(s1, s3), u3t = csub(s1, s3);
    float2 u3 = make_float2(-(float)S * u3t.y, (float)S * u3t.x);
    v[0] = cadd(u0, u1); v[1] = csub(u0, u1); v[2] = cadd(u2, u3); v[3] = csub(u2, u3);
    float2 w0 = cadd(d0, d2), w2 = csub(d0, d2);
    float2 w1 = cadd(d1, d3), w3t = csub(d1, d3);
    float2 w3 = make_float2(-(float)S * w3t.y, (float)S * w3t.x);
    v[4] = cadd(w0, w1); v[5] = csub(w0, w1); v[6] = cadd(w2, w3); v[7] = csub(w2, w3);
}

// ---------------------------------------------------------------------------
// 4-pt FFT, natural order. X[k] = sum_n x[n] e^{S*2pi i nk/4}
// ---------------------------------------------------------------------------
template <int S>
__device__ __forceinline__ void fft4(float2& a, float2& b, float2& c, float2& d) {
    float2 t0 = cadd(a, c), t1 = csub(a, c);
    float2 t2 = cadd(b, d), t3 = csub(b, d);
    a = cadd(t0, t2);
    c = csub(t0, t2);
    b = make_float2(t1.x - (float)S * t3.y, t1.y + (float)S * t3.x);
    d = make_float2(t1.x + (float)S * t3.y, t1.y - (float)S * t3.x);
}

// 16-pt FFT in registers, natural order in/out, radix 4x4.
template <int S>
__device__ __forceinline__ void fft16(float2 v[16]) {
    const float CS[10] = {1.f, 0.92387953f, 0.70710678f, 0.38268343f, 0.f,
                          -0.38268343f, -0.70710678f, -0.92387953f, -1.f, -0.92387953f};
    const float SN[10] = {0.f, 0.38268343f, 0.70710678f, 0.92387953f, 1.f,
                          0.92387953f, 0.70710678f, 0.38268343f, 0.f, -0.38268343f};
    float2 A[4][4];
#pragma unroll
    for (int j = 0; j < 4; ++j) {
        A[j][0] = v[j]; A[j][1] = v[4 + j]; A[j][2] = v[8 + j]; A[j][3] = v[12 + j];
        fft4<S>(A[j][0], A[j][1], A[j][2], A[j][3]);
#pragma unroll
        for (int k0 = 0; k0 < 4; ++k0) {
            int m = j * k0;
            float2 tw = make_float2(CS[m], (float)S * SN[m]);
            A[j][k0] = cmul(A[j][k0], tw);
        }
    }
#pragma unroll
    for (int k0 = 0; k0 < 4; ++k0) {
        fft4<S>(A[0][k0], A[1][k0], A[2][k0], A[3][k0]);
        v[k0] = A[0][k0]; v[k0 + 4] = A[1][k0]; v[k0 + 8] = A[2][k0]; v[k0 + 12] = A[3][k0];
    }
}

// ---------------------------------------------------------------------------
// Radix-8x8 64-pt FFT along W, real fp32 input -> bf16 complex. wg per (b,t,h).
// ---------------------------------------------------------------------------
__global__ __launch_bounds__(256) void k_fft_w_fwd(const float* __restrict__ x,
                                                   unsigned* __restrict__ X) {
    __shared__ float2 ex[64 * 65];
    const int brev[8] = {0, 4, 2, 6, 1, 5, 3, 7};
    int tid = threadIdx.x;
    int j = tid >> 5, cl = tid & 31;
    int base = blockIdx.x * 4096;
    float2 v[2][8];
#pragma unroll
    for (int q = 0; q < 2; ++q) {
        int c = cl + 32 * q;
#pragma unroll
        for (int n1 = 0; n1 < 8; ++n1)
            v[q][n1] = make_float2(x[base + (8 * n1 + j) * 64 + c], 0.f);
    }
    float sj, cj; sincosf(-TWO_PI * (float)j / 64.f, &sj, &cj);
    float2 w1 = make_float2(cj, sj);
#pragma unroll
    for (int q = 0; q < 2; ++q) {
        fft8<-1>(v[q]);
        int c = cl + 32 * q;
        float2 tw = make_float2(1.f, 0.f);
#pragma unroll
        for (int k0 = 0; k0 < 8; ++k0) {
            ex[c * 65 + j * 8 + k0] = cmul(v[q][brev[k0]], tw);
            tw = cmul(tw, w1);
        }
    }
    __syncthreads();
#pragma unroll
    for (int q = 0; q < 2; ++q) {
        int c = cl + 32 * q;
        float2 z[8];
#pragma unroll
        for (int n0 = 0; n0 < 8; ++n0) z[n0] = ex[c * 65 + n0 * 8 + j];
        fft8<-1>(z);
#pragma unroll
        for (int m = 0; m < 8; ++m)
            X[base + (j + 8 * brev[m]) * 64 + c] = bfpack(z[m]);
    }
}

// ---------------------------------------------------------------------------
// Radix-8x8 64-pt FFT along H, bf16 complex in-place. wg per (b,t,w).
// Output scaled by 1/(1<<SHIFT).
// ---------------------------------------------------------------------------
template <int S, int SHIFT>
__global__ __launch_bounds__(256) void k_fft_h(unsigned* __restrict__ X) {
    __shared__ float2 ex[64 * 65];
    const int brev[8] = {0, 4, 2, 6, 1, 5, 3, 7};
    const float sc = 1.0f / (float)(1 << SHIFT);
    int tid = threadIdx.x;
    int j = tid >> 5, cl = tid & 31;
    int s = blockIdx.x;
    int bt = s >> 6, w = s & 63;
    int base = bt * ST_ + w * 64;
    float2 v[2][8];
#pragma unroll
    for (int q = 0; q < 2; ++q) {
        int c = cl + 32 * q;
#pragma unroll
        for (int n1 = 0; n1 < 8; ++n1)
            v[q][n1] = bfunpack(X[base + (8 * n1 + j) * SH_ + c]);
    }
    float sj, cj; sincosf((float)S * TWO_PI * (float)j / 64.f, &sj, &cj);
    float2 w1 = make_float2(cj, sj);
#pragma unroll
    for (int q = 0; q < 2; ++q) {
        fft8<S>(v[q]);
        int c = cl + 32 * q;
        float2 tw = make_float2(1.f, 0.f);
#pragma unroll
        for (int k0 = 0; k0 < 8; ++k0) {
            ex[c * 65 + j * 8 + k0] = cmul(v[q][brev[k0]], tw);
            tw = cmul(tw, w1);
        }
    }
    __syncthreads();
#pragma unroll
    for (int q = 0; q < 2; ++q) {
        int c = cl + 32 * q;
        float2 z[8];
#pragma unroll
        for (int n0 = 0; n0 < 8; ++n0) z[n0] = ex[c * 65 + n0 * 8 + j];
        fft8<S>(z);
#pragma unroll
        for (int m = 0; m < 8; ++m) {
            float2 o = make_float2(z[m].x * sc, z[m].y * sc);
            X[base + (j + 8 * brev[m]) * SH_ + c] = bfpack(o);
        }
    }
}

// ---------------------------------------------------------------------------
// Fused: FFT-16 fwd along T + gates + scan + FFT-16 inv along T, in registers.
// 256 thr = 4 sites (b,h,w) x 64 channels; one wave == one site.
// Output scaled by 1/16.
// ---------------------------------------------------------------------------
__global__ __launch_bounds__(256) void k_mid(
    const float* __restrict__ x, unsigned* __restrict__ X,
    const float* __restrict__ Ak, const float* __restrict__ Bk,
    const float* __restrict__ fb, const float* __restrict__ fs,
    const float* __restrict__ ib, const float* __restrict__ isc_,
    const float* __restrict__ dW, const float* __restrict__ db) {
    const float CT[16] = {1.f, 0.9238795f, 0.7071068f, 0.3826834f, 0.f, -0.3826834f,
                          -0.7071068f, -0.9238795f, -1.f, -0.9238795f, -0.7071068f,
                          -0.3826834f, 0.f, 0.3826834f, 0.7071068f, 0.9238795f};
    const float SN[16] = {0.f, 0.3826834f, 0.7071068f, 0.9238795f, 1.f, 0.9238795f,
                          0.7071068f, 0.3826834f, 0.f, -0.3826834f, -0.7071068f,
                          -0.9238795f, -1.f, -0.9238795f, -0.7071068f, -0.3826834f};
    int tid = threadIdx.x;
    int g = tid >> 6, c = tid & 63;
    int site = blockIdx.x * 4 + g;
    int b = site >> 12, hw = site & 4095;
    int h = hw >> 6, w = hw & 63;
    int base = b * SB_ + hw * 64;

    float wcol[64];
#pragma unroll
    for (int d = 0; d < 64; ++d) wcol[d] = dW[(d << 6) + c];

    float sh, ch; sincosf(TWO_PI * (float)h / 64.0f, &sh, &ch);
    float sw, cw; sincosf(TWO_PI * (float)w / 64.0f, &sw, &cw);
    float2 eh[3] = { make_float2(ch, sh), make_float2(1.f, 0.f), make_float2(ch, -sh) };
    float2 ew[3] = { make_float2(cw, sw), make_float2(1.f, 0.f), make_float2(cw, -sw) };
    float2 GA[3], GB[3];
#pragma unroll
    for (int kt = 0; kt < 3; ++kt) { GA[kt] = make_float2(0.f, 0.f); GB[kt] = make_float2(0.f, 0.f); }
#pragma unroll
    for (int kh = 0; kh < 3; ++kh) {
#pragma unroll
        for (int kw = 0; kw < 3; ++kw) {
            float2 e = cmul(eh[kh], ew[kw]);
#pragma unroll
            for (int kt = 0; kt < 3; ++kt) {
                float ka = Ak[((c * 3 + kt) * 3 + kh) * 3 + kw];
                float kb = Bk[((c * 3 + kt) * 3 + kh) * 3 + kw];
                GA[kt].x = fmaf(ka, e.x, GA[kt].x);
                GA[kt].y = fmaf(ka, e.y, GA[kt].y);
                GB[kt].x = fmaf(kb, e.x, GB[kt].x);
                GB[kt].y = fmaf(kb, e.y, GB[kt].y);
            }
        }
    }
    float fbc = fb[c], fsc = fs[c], ibc = ib[c], iscv = isc_[c], dbc = db[c];

    float2 v[16];
    float xv[16];
#pragma unroll
    for (int t = 0; t < 16; ++t) {
        v[t] = bfunpack(X[base + t * ST_ + c]);
        xv[t] = x[base + t * ST_ + c];
    }

    fft16<-1>(v);

    const float* __restrict__ xrow = x + __builtin_amdgcn_readfirstlane(base);

    float2 hv = make_float2(0.f, 0.f);
#pragma unroll
    for (int t = 0; t < 16; ++t) {
        float ct = CT[t], st = SN[t];
        float2 Af, Bf;
        Af.x = GA[1].x + ct * (GA[0].x + GA[2].x) - st * (GA[0].y - GA[2].y);
        Af.y = GA[1].y + ct * (GA[0].y + GA[2].y) + st * (GA[0].x - GA[2].x);
        Bf.x = GB[1].x + ct * (GB[0].x + GB[2].x) - st * (GB[0].y - GB[2].y);
        Bf.y = GB[1].y + ct * (GB[0].y + GB[2].y) + st * (GB[0].x - GB[2].x);

        float xc = xv[t];
        float fg  = __builtin_amdgcn_rcpf(1.f + __expf(-(fbc + fsc * xc)));
        float igv = __builtin_amdgcn_rcpf(1.f + __expf(-(ibc + iscv * xc)));
        float dot = dbc;
#pragma unroll
        for (int d = 0; d < 64; ++d)
            dot = fmaf(xrow[t * ST_ + d], wcol[d], dot);
        float delta = (dot > 20.f) ? dot : __logf(1.f + __expf(dot));

        float sR = igv * delta;
        float2 bbv;
        bbv.x = sR * (Bf.x * v[t].x - Bf.y * v[t].y);
        bbv.y = sR * (Bf.x * v[t].y + Bf.y * v[t].x);
        float2 av = make_float2(fg * Af.x, fg * Af.y);
        float2 nh;
        nh.x = av.x * hv.x - av.y * hv.y + bbv.x;
        nh.y = av.x * hv.y + av.y * hv.x + bbv.y;
        hv = nh;
        v[t] = hv;
    }

    fft16<1>(v);

#pragma unroll
    for (int t = 0; t < 16; ++t) {
        float2 o = make_float2(v[t].x * 0.0625f, v[t].y * 0.0625f);
        X[base + t * ST_ + c] = bfpack(o);
    }
}

// ---------------------------------------------------------------------------
// Radix-8x8 inverse 64-pt FFT along W + real output * 1/64.
// ---------------------------------------------------------------------------
__global__ __launch_bounds__(256) void k_fft_w_inv_out(const unsigned* __restrict__ X,
                                                       float* __restrict__ out) {
    __shared__ float2 ex[64 * 65];
    const int brev[8] = {0, 4, 2, 6, 1, 5, 3, 7};
    int tid = threadIdx.x;
    int j = tid >> 5, cl = tid & 31;
    int base = blockIdx.x * 4096;
    float2 v[2][8];
#pragma unroll
    for (int q = 0; q < 2; ++q) {
        int c = cl + 32 * q;
#pragma unroll
        for (int n1 = 0; n1 < 8; ++n1)
            v[q][n1] = bfunpack(X[base + (8 * n1 + j) * 64 + c]);
    }
    float sj, cj; sincosf(TWO_PI * (float)j / 64.f, &sj, &cj);
    float2 w1 = make_float2(cj, sj);
#pragma unroll
    for (int q = 0; q < 2; ++q) {
        fft8<1>(v[q]);
        int c = cl + 32 * q;
        float2 tw = make_float2(1.f, 0.f);
#pragma unroll
        for (int k0 = 0; k0 < 8; ++k0) {
            ex[c * 65 + j * 8 + k0] = cmul(v[q][brev[k0]], tw);
            tw = cmul(tw, w1);
        }
    }
    __syncthreads();
#pragma unroll
    for (int q = 0; q < 2; ++q) {
        int c = cl + 32 * q;
        float2 z[8];
#pragma unroll
        for (int n0 = 0; n0 < 8; ++n0) z[n0] = ex[c * 65 + n0 * 8 + j];
        fft8<1>(z);
#pragma unroll
        for (int m = 0; m < 8; ++m)
            out[base + (j + 8 * brev[m]) * 64 + c] = z[m].x * (1.0f / 64.0f);
    }
}

extern "C" void kernel_launch(void* const* d_in, const int* in_sizes, int n_in,
                              void* d_out, int out_size, void* d_ws, size_t ws_size,
                              hipStream_t stream) {
    const float* x   = (const float*)d_in[0];
    const float* Ak  = (const float*)d_in[1];
    const float* Bk  = (const float*)d_in[2];
    const float* fb  = (const float*)d_in[3];
    const float* fs  = (const float*)d_in[4];
    const float* ib  = (const float*)d_in[5];
    const float* is_ = (const float*)d_in[6];
    const float* dW  = (const float*)d_in[7];
    const float* db  = (const float*)d_in[8];
    float* out = (float*)d_out;
    unsigned* X = (unsigned*)d_ws;  // (B,T,H,W,C) bf16 complex pairs = 33.5 MB

    k_fft_w_fwd<<<Bb * Tt * Hh, 256, 0, stream>>>(x, X);
    k_fft_h<-1, 0><<<Bb * Tt * Ww, 256, 0, stream>>>(X);
    k_mid<<<(Bb * Hh * Ww) / 4, 256, 0, stream>>>(x, X, Ak, Bk, fb, fs, ib, is_, dW, db);
    k_fft_h<1, 6><<<Bb * Tt * Ww, 256, 0, stream>>>(X);
    k_fft_w_inv_out<<<Bb * Tt * Hh, 256, 0, stream>>>(X, out);
}

// Round 5
// 174.226 us; speedup vs baseline: 5.7693x; 1.4102x over previous
//
#include <hip/hip_runtime.h>
#include <math.h>

// Problem dims
#define Bb 2
#define Tt 16
#define Hh 64
#define Ww 64
#define Cc 64
#define ST_ (Hh*Ww*Cc)    // 262144
#define SH_ (Ww*Cc)       // 4096
#define SB_ (Tt*Hh*Ww*Cc) // 4194304

#define TWO_PI 6.2831853071795864769f

typedef __attribute__((ext_vector_type(8))) short bf16x8;
typedef __attribute__((ext_vector_type(4))) float f32x4;

__device__ __forceinline__ float2 cmul(float2 a, float2 b) {
    return make_float2(fmaf(a.x, b.x, -a.y * b.y), fmaf(a.x, b.y, a.y * b.x));
}
__device__ __forceinline__ float2 cadd(float2 a, float2 b) { return make_float2(a.x + b.x, a.y + b.y); }
__device__ __forceinline__ float2 csub(float2 a, float2 b) { return make_float2(a.x - b.x, a.y - b.y); }

// bf16 pair pack/unpack (a -> low 16, b -> high 16). RNE; range = fp32.
__device__ __forceinline__ unsigned bfpack(float2 f) {
    unsigned r = __float_as_uint(f.x);
    unsigned i = __float_as_uint(f.y);
    r = (r + 0x7fffu + ((r >> 16) & 1u)) >> 16;
    i = (i + 0x7fffu + ((i >> 16) & 1u)) >> 16;
    return r | (i << 16);
}
__device__ __forceinline__ float2 bfunpack(unsigned u) {
    return make_float2(__uint_as_float(u << 16), __uint_as_float(u & 0xffff0000u));
}

// ---------------------------------------------------------------------------
// 8-pt DIF FFT in-place; output order brev3={0,4,2,6,1,5,3,7}
// ---------------------------------------------------------------------------
template <int S>
__device__ __forceinline__ void fft8(float2 v[8]) {
    const float R = 0.70710678118654752f;
    float2 s0 = cadd(v[0], v[4]), d0 = csub(v[0], v[4]);
    float2 s1 = cadd(v[1], v[5]), d1 = csub(v[1], v[5]);
    float2 s2 = cadd(v[2], v[6]), d2 = csub(v[2], v[6]);
    float2 s3 = cadd(v[3], v[7]), d3 = csub(v[3], v[7]);
    d1 = make_float2(R * (d1.x - (float)S * d1.y), R * ((float)S * d1.x + d1.y));
    { float2 t = d2; d2 = make_float2(-(float)S * t.y, (float)S * t.x); }
    d3 = make_float2(R * (-d3.x - (float)S * d3.y), R * ((float)S * d3.x - d3.y));
    float2 u0 = cadd(s0, s2), u2 = csub(s0, s2);
    float2 u1 = cadd(s1, s3), u3t = csub(s1, s3);
    float2 u3 = make_float2(-(float)S * u3t.y, (float)S * u3t.x);
    v[0] = cadd(u0, u1); v[1] = csub(u0, u1); v[2] = cadd(u2, u3); v[3] = csub(u2, u3);
    float2 w0 = cadd(d0, d2), w2 = csub(d0, d2);
    float2 w1 = cadd(d1, d3), w3t = csub(d1, d3);
    float2 w3 = make_float2(-(float)S * w3t.y, (float)S * w3t.x);
    v[4] = cadd(w0, w1); v[5] = csub(w0, w1); v[6] = cadd(w2, w3); v[7] = csub(w2, w3);
}

template <int S>
__device__ __forceinline__ void fft4(float2& a, float2& b, float2& c, float2& d) {
    float2 t0 = cadd(a, c), t1 = csub(a, c);
    float2 t2 = cadd(b, d), t3 = csub(b, d);
    a = cadd(t0, t2);
    c = csub(t0, t2);
    b = make_float2(t1.x - (float)S * t3.y, t1.y + (float)S * t3.x);
    d = make_float2(t1.x + (float)S * t3.y, t1.y - (float)S * t3.x);
}

// 16-pt FFT in registers, natural order in/out, radix 4x4.
template <int S>
__device__ __forceinline__ void fft16(float2 v[16]) {
    const float CS[10] = {1.f, 0.92387953f, 0.70710678f, 0.38268343f, 0.f,
                          -0.38268343f, -0.70710678f, -0.92387953f, -1.f, -0.92387953f};
    const float SN[10] = {0.f, 0.38268343f, 0.70710678f, 0.92387953f, 1.f,
                          0.92387953f, 0.70710678f, 0.38268343f, 0.f, -0.38268343f};
    float2 A[4][4];
#pragma unroll
    for (int j = 0; j < 4; ++j) {
        A[j][0] = v[j]; A[j][1] = v[4 + j]; A[j][2] = v[8 + j]; A[j][3] = v[12 + j];
        fft4<S>(A[j][0], A[j][1], A[j][2], A[j][3]);
#pragma unroll
        for (int k0 = 0; k0 < 4; ++k0) {
            int m = j * k0;
            float2 tw = make_float2(CS[m], (float)S * SN[m]);
            A[j][k0] = cmul(A[j][k0], tw);
        }
    }
#pragma unroll
    for (int k0 = 0; k0 < 4; ++k0) {
        fft4<S>(A[0][k0], A[1][k0], A[2][k0], A[3][k0]);
        v[k0] = A[0][k0]; v[k0 + 4] = A[1][k0]; v[k0 + 8] = A[2][k0]; v[k0 + 12] = A[3][k0];
    }
}

// ---------------------------------------------------------------------------
// Radix-8x8 64-pt FFT along W, real fp32 input -> bf16 complex. wg per (b,t,h).
// ---------------------------------------------------------------------------
__global__ __launch_bounds__(256) void k_fft_w_fwd(const float* __restrict__ x,
                                                   unsigned* __restrict__ X) {
    __shared__ float2 ex[64 * 65];
    const int brev[8] = {0, 4, 2, 6, 1, 5, 3, 7};
    int tid = threadIdx.x;
    int j = tid >> 5, cl = tid & 31;
    int base = blockIdx.x * 4096;
    float2 v[2][8];
#pragma unroll
    for (int q = 0; q < 2; ++q) {
        int c = cl + 32 * q;
#pragma unroll
        for (int n1 = 0; n1 < 8; ++n1)
            v[q][n1] = make_float2(x[base + (8 * n1 + j) * 64 + c], 0.f);
    }
    float sj, cj; sincosf(-TWO_PI * (float)j / 64.f, &sj, &cj);
    float2 w1 = make_float2(cj, sj);
#pragma unroll
    for (int q = 0; q < 2; ++q) {
        fft8<-1>(v[q]);
        int c = cl + 32 * q;
        float2 tw = make_float2(1.f, 0.f);
#pragma unroll
        for (int k0 = 0; k0 < 8; ++k0) {
            ex[c * 65 + j * 8 + k0] = cmul(v[q][brev[k0]], tw);
            tw = cmul(tw, w1);
        }
    }
    __syncthreads();
#pragma unroll
    for (int q = 0; q < 2; ++q) {
        int c = cl + 32 * q;
        float2 z[8];
#pragma unroll
        for (int n0 = 0; n0 < 8; ++n0) z[n0] = ex[c * 65 + n0 * 8 + j];
        fft8<-1>(z);
#pragma unroll
        for (int m = 0; m < 8; ++m)
            X[base + (j + 8 * brev[m]) * 64 + c] = bfpack(z[m]);
    }
}

// ---------------------------------------------------------------------------
// Radix-8x8 64-pt FFT along H, bf16 complex in-place. wg per (b,t,w).
// ---------------------------------------------------------------------------
template <int S, int SHIFT>
__global__ __launch_bounds__(256) void k_fft_h(unsigned* __restrict__ X) {
    __shared__ float2 ex[64 * 65];
    const int brev[8] = {0, 4, 2, 6, 1, 5, 3, 7};
    const float sc = 1.0f / (float)(1 << SHIFT);
    int tid = threadIdx.x;
    int j = tid >> 5, cl = tid & 31;
    int s = blockIdx.x;
    int bt = s >> 6, w = s & 63;
    int base = bt * ST_ + w * 64;
    float2 v[2][8];
#pragma unroll
    for (int q = 0; q < 2; ++q) {
        int c = cl + 32 * q;
#pragma unroll
        for (int n1 = 0; n1 < 8; ++n1)
            v[q][n1] = bfunpack(X[base + (8 * n1 + j) * SH_ + c]);
    }
    float sj, cj; sincosf((float)S * TWO_PI * (float)j / 64.f, &sj, &cj);
    float2 w1 = make_float2(cj, sj);
#pragma unroll
    for (int q = 0; q < 2; ++q) {
        fft8<S>(v[q]);
        int c = cl + 32 * q;
        float2 tw = make_float2(1.f, 0.f);
#pragma unroll
        for (int k0 = 0; k0 < 8; ++k0) {
            ex[c * 65 + j * 8 + k0] = cmul(v[q][brev[k0]], tw);
            tw = cmul(tw, w1);
        }
    }
    __syncthreads();
#pragma unroll
    for (int q = 0; q < 2; ++q) {
        int c = cl + 32 * q;
        float2 z[8];
#pragma unroll
        for (int n0 = 0; n0 < 8; ++n0) z[n0] = ex[c * 65 + n0 * 8 + j];
        fft8<S>(z);
#pragma unroll
        for (int m = 0; m < 8; ++m) {
            float2 o = make_float2(z[m].x * sc, z[m].y * sc);
            X[base + (j + 8 * brev[m]) * SH_ + c] = bfpack(o);
        }
    }
}

// ---------------------------------------------------------------------------
// Fused: FFT-16 fwd along T + gates + MFMA delta-matmul + scan + FFT-16 inv.
// 256 thr = 4 waves = 4 sites (b,h,w); lane = channel c.
// delta: D[t][c] = softplus(sum_d x[t][d] W[d][c] + db[c]) via
// 8x mfma_f32_16x16x32_bf16 per wave (M=16 t, N=64 c, K=64 d).
// Output scaled by 1/16.
// ---------------------------------------------------------------------------
__global__ __launch_bounds__(256) void k_mid(
    const float* __restrict__ x, unsigned* __restrict__ X,
    const float* __restrict__ Ak, const float* __restrict__ Bk,
    const float* __restrict__ fb, const float* __restrict__ fs,
    const float* __restrict__ ib, const float* __restrict__ isc_,
    const float* __restrict__ dW, const float* __restrict__ db) {
    const float CT[16] = {1.f, 0.9238795f, 0.7071068f, 0.3826834f, 0.f, -0.3826834f,
                          -0.7071068f, -0.9238795f, -1.f, -0.9238795f, -0.7071068f,
                          -0.3826834f, 0.f, 0.3826834f, 0.7071068f, 0.9238795f};
    const float SN[16] = {0.f, 0.3826834f, 0.7071068f, 0.9238795f, 1.f, 0.9238795f,
                          0.7071068f, 0.3826834f, 0.f, -0.3826834f, -0.7071068f,
                          -0.9238795f, -1.f, -0.9238795f, -0.7071068f, -0.3826834f};
    __shared__ float Wl[4096];                      // dW staged, [d*64+c]
    __shared__ float Akl[1728], Bkl[1728];          // kernels staged, [c*27+off]
    __shared__ __align__(16) float xs[4][16 * 68 + 4];  // per-wave x rows (stride 68); reused for delta

    int tid = threadIdx.x;
    int g = tid >> 6, lane = tid & 63;
    int c = lane;
    int site = blockIdx.x * 4 + g;
    int b = site >> 12, hw = site & 4095;
    int h = hw >> 6, w = hw & 63;
    int base = b * SB_ + hw * 64;

    // cooperative staging (coalesced, conflict-free writes)
    for (int i = tid; i < 4096; i += 256) Wl[i] = dW[i];
    for (int i = tid; i < 1728; i += 256) { Akl[i] = Ak[i]; Bkl[i] = Bk[i]; }

    // per-lane loads: x and X T-lines
    float xv[16];
    float2 v[16];
#pragma unroll
    for (int t = 0; t < 16; ++t) {
        xv[t] = x[base + t * ST_ + c];
        v[t] = bfunpack(X[base + t * ST_ + c]);
    }
#pragma unroll
    for (int t = 0; t < 16; ++t) xs[g][t * 68 + c] = xv[t];  // bank (4t+c)%32: 2-way, free
    __syncthreads();

    // ---- MFMA delta matmul ----
    int m = lane & 15, q = lane >> 4;
    bf16x8 Afrag[2];
#pragma unroll
    for (int ka = 0; ka < 2; ++ka) {
        int d0 = ka * 32 + q * 8;
        const float* p = &xs[g][m * 68 + d0];          // 16B-aligned
        float4 f0 = *(const float4*)p;
        float4 f1 = *(const float4*)(p + 4);
        union { bf16x8 v8; unsigned u[4]; } U;
        U.u[0] = bfpack(make_float2(f0.x, f0.y));
        U.u[1] = bfpack(make_float2(f0.z, f0.w));
        U.u[2] = bfpack(make_float2(f1.x, f1.y));
        U.u[3] = bfpack(make_float2(f1.z, f1.w));
        Afrag[ka] = U.v8;
    }
#pragma unroll
    for (int nt = 0; nt < 4; ++nt) {
        int ccol = m + 16 * nt;
        float dbn = db[ccol];
        f32x4 acc = {dbn, dbn, dbn, dbn};
#pragma unroll
        for (int ka = 0; ka < 2; ++ka) {
            int kb = ka * 32 + q * 8;
            union { bf16x8 v8; unsigned u[4]; } Ub;
#pragma unroll
            for (int p2 = 0; p2 < 4; ++p2)
                Ub.u[p2] = bfpack(make_float2(Wl[(kb + 2 * p2) * 64 + ccol],
                                              Wl[(kb + 2 * p2 + 1) * 64 + ccol]));
            acc = __builtin_amdgcn_mfma_f32_16x16x32_bf16(Afrag[ka], Ub.v8, acc, 0, 0, 0);
        }
        // D layout: row t=(q*4+reg), col=ccol -> back into xs (raw dot incl. db)
#pragma unroll
        for (int reg = 0; reg < 4; ++reg)
            xs[g][(q * 4 + reg) * 68 + ccol] = acc[reg];
    }

    // ---- A_f/B_f generators from the 27 taps (LDS-staged, 2-way banks) ----
    float sh, ch; sincosf(TWO_PI * (float)h / 64.0f, &sh, &ch);
    float sw, cw; sincosf(TWO_PI * (float)w / 64.0f, &sw, &cw);
    float2 eh[3] = { make_float2(ch, sh), make_float2(1.f, 0.f), make_float2(ch, -sh) };
    float2 ew[3] = { make_float2(cw, sw), make_float2(1.f, 0.f), make_float2(cw, -sw) };
    float2 GA[3], GB[3];
#pragma unroll
    for (int kt = 0; kt < 3; ++kt) { GA[kt] = make_float2(0.f, 0.f); GB[kt] = make_float2(0.f, 0.f); }
#pragma unroll
    for (int kh = 0; kh < 3; ++kh) {
#pragma unroll
        for (int kw = 0; kw < 3; ++kw) {
            float2 e = cmul(eh[kh], ew[kw]);
#pragma unroll
            for (int kt = 0; kt < 3; ++kt) {
                float ka = Akl[c * 27 + kt * 9 + kh * 3 + kw];
                float kb = Bkl[c * 27 + kt * 9 + kh * 3 + kw];
                GA[kt].x = fmaf(ka, e.x, GA[kt].x);
                GA[kt].y = fmaf(ka, e.y, GA[kt].y);
                GB[kt].x = fmaf(kb, e.x, GB[kt].x);
                GB[kt].y = fmaf(kb, e.y, GB[kt].y);
            }
        }
    }
    float fbc = fb[c], fsc = fs[c], ibc = ib[c], iscv = isc_[c];

    fft16<-1>(v);
    __syncthreads();  // delta (in xs) visible / ordered

    float delta_raw[16];
#pragma unroll
    for (int t = 0; t < 16; ++t) delta_raw[t] = xs[g][t * 68 + c];

    float2 hv = make_float2(0.f, 0.f);
#pragma unroll
    for (int t = 0; t < 16; ++t) {
        float ct = CT[t], st = SN[t];
        float2 Af, Bf;
        Af.x = GA[1].x + ct * (GA[0].x + GA[2].x) - st * (GA[0].y - GA[2].y);
        Af.y = GA[1].y + ct * (GA[0].y + GA[2].y) + st * (GA[0].x - GA[2].x);
        Bf.x = GB[1].x + ct * (GB[0].x + GB[2].x) - st * (GB[0].y - GB[2].y);
        Bf.y = GB[1].y + ct * (GB[0].y + GB[2].y) + st * (GB[0].x - GB[2].x);

        float xc = xv[t];
        float fg  = __builtin_amdgcn_rcpf(1.f + __expf(-(fbc + fsc * xc)));
        float igv = __builtin_amdgcn_rcpf(1.f + __expf(-(ibc + iscv * xc)));
        float dot = delta_raw[t];
        float delta = (dot > 20.f) ? dot : __logf(1.f + __expf(dot));

        float sR = igv * delta;
        float2 bbv;
        bbv.x = sR * (Bf.x * v[t].x - Bf.y * v[t].y);
        bbv.y = sR * (Bf.x * v[t].y + Bf.y * v[t].x);
        float2 av = make_float2(fg * Af.x, fg * Af.y);
        float2 nh;
        nh.x = av.x * hv.x - av.y * hv.y + bbv.x;
        nh.y = av.x * hv.y + av.y * hv.x + bbv.y;
        hv = nh;
        v[t] = hv;
    }

    fft16<1>(v);

#pragma unroll
    for (int t = 0; t < 16; ++t) {
        float2 o = make_float2(v[t].x * 0.0625f, v[t].y * 0.0625f);
        X[base + t * ST_ + c] = bfpack(o);
    }
}

// ---------------------------------------------------------------------------
// Radix-8x8 inverse 64-pt FFT along W + real output * 1/64.
// ---------------------------------------------------------------------------
__global__ __launch_bounds__(256) void k_fft_w_inv_out(const unsigned* __restrict__ X,
                                                       float* __restrict__ out) {
    __shared__ float2 ex[64 * 65];
    const int brev[8] = {0, 4, 2, 6, 1, 5, 3, 7};
    int tid = threadIdx.x;
    int j = tid >> 5, cl = tid & 31;
    int base = blockIdx.x * 4096;
    float2 v[2][8];
#pragma unroll
    for (int q = 0; q < 2; ++q) {
        int c = cl + 32 * q;
#pragma unroll
        for (int n1 = 0; n1 < 8; ++n1)
            v[q][n1] = bfunpack(X[base + (8 * n1 + j) * 64 + c]);
    }
    float sj, cj; sincosf(TWO_PI * (float)j / 64.f, &sj, &cj);
    float2 w1 = make_float2(cj, sj);
#pragma unroll
    for (int q = 0; q < 2; ++q) {
        fft8<1>(v[q]);
        int c = cl + 32 * q;
        float2 tw = make_float2(1.f, 0.f);
#pragma unroll
        for (int k0 = 0; k0 < 8; ++k0) {
            ex[c * 65 + j * 8 + k0] = cmul(v[q][brev[k0]], tw);
            tw = cmul(tw, w1);
        }
    }
    __syncthreads();
#pragma unroll
    for (int q = 0; q < 2; ++q) {
        int c = cl + 32 * q;
        float2 z[8];
#pragma unroll
        for (int n0 = 0; n0 < 8; ++n0) z[n0] = ex[c * 65 + n0 * 8 + j];
        fft8<1>(z);
#pragma unroll
        for (int m = 0; m < 8; ++m)
            out[base + (j + 8 * brev[m]) * 64 + c] = z[m].x * (1.0f / 64.0f);
    }
}

extern "C" void kernel_launch(void* const* d_in, const int* in_sizes, int n_in,
                              void* d_out, int out_size, void* d_ws, size_t ws_size,
                              hipStream_t stream) {
    const float* x   = (const float*)d_in[0];
    const float* Ak  = (const float*)d_in[1];
    const float* Bk  = (const float*)d_in[2];
    const float* fb  = (const float*)d_in[3];
    const float* fs  = (const float*)d_in[4];
    const float* ib  = (const float*)d_in[5];
    const float* is_ = (const float*)d_in[6];
    const float* dW  = (const float*)d_in[7];
    const float* db  = (const float*)d_in[8];
    float* out = (float*)d_out;
    unsigned* X = (unsigned*)d_ws;  // (B,T,H,W,C) bf16 complex pairs = 33.5 MB

    k_fft_w_fwd<<<Bb * Tt * Hh, 256, 0, stream>>>(x, X);
    k_fft_h<-1, 0><<<Bb * Tt * Ww, 256, 0, stream>>>(X);
    k_mid<<<(Bb * Hh * Ww) / 4, 256, 0, stream>>>(x, X, Ak, Bk, fb, fs, ib, is_, dW, db);
    k_fft_h<1, 6><<<Bb * Tt * Ww, 256, 0, stream>>>(X);
    k_fft_w_inv_out<<<Bb * Tt * Hh, 256, 0, stream>>>(X, out);
}

// Round 6
// 173.612 us; speedup vs baseline: 5.7897x; 1.0035x over previous
//
#include <hip/hip_runtime.h>
#include <math.h>

// Problem dims
#define Bb 2
#define Tt 16
#define Hh 64
#define Ww 64
#define Cc 64
#define ST_ (Hh*Ww*Cc)    // 262144
#define SH_ (Ww*Cc)       // 4096
#define SB_ (Tt*Hh*Ww*Cc) // 4194304
#define XELEMS (Bb*Tt*Hh*Ww*Cc)  // 8388608

#define TWO_PI 6.2831853071795864769f

typedef __attribute__((ext_vector_type(8))) short bf16x8;
typedef __attribute__((ext_vector_type(4))) float f32x4;

__device__ __forceinline__ float2 cmul(float2 a, float2 b) {
    return make_float2(fmaf(a.x, b.x, -a.y * b.y), fmaf(a.x, b.y, a.y * b.x));
}
__device__ __forceinline__ float2 cadd(float2 a, float2 b) { return make_float2(a.x + b.x, a.y + b.y); }
__device__ __forceinline__ float2 csub(float2 a, float2 b) { return make_float2(a.x - b.x, a.y - b.y); }

// bf16 pair pack/unpack (x -> low 16, y -> high 16). RNE; range = fp32.
__device__ __forceinline__ unsigned bfpack(float2 f) {
    unsigned r = __float_as_uint(f.x);
    unsigned i = __float_as_uint(f.y);
    r = (r + 0x7fffu + ((r >> 16) & 1u)) >> 16;
    i = (i + 0x7fffu + ((i >> 16) & 1u)) >> 16;
    return r | (i << 16);
}
__device__ __forceinline__ float2 bfunpack(unsigned u) {
    return make_float2(__uint_as_float(u << 16), __uint_as_float(u & 0xffff0000u));
}

// ---------------------------------------------------------------------------
// 8-pt DIF FFT in-place; output order brev3={0,4,2,6,1,5,3,7}
// ---------------------------------------------------------------------------
template <int S>
__device__ __forceinline__ void fft8(float2 v[8]) {
    const float R = 0.70710678118654752f;
    float2 s0 = cadd(v[0], v[4]), d0 = csub(v[0], v[4]);
    float2 s1 = cadd(v[1], v[5]), d1 = csub(v[1], v[5]);
    float2 s2 = cadd(v[2], v[6]), d2 = csub(v[2], v[6]);
    float2 s3 = cadd(v[3], v[7]), d3 = csub(v[3], v[7]);
    d1 = make_float2(R * (d1.x - (float)S * d1.y), R * ((float)S * d1.x + d1.y));
    { float2 t = d2; d2 = make_float2(-(float)S * t.y, (float)S * t.x); }
    d3 = make_float2(R * (-d3.x - (float)S * d3.y), R * ((float)S * d3.x - d3.y));
    float2 u0 = cadd(s0, s2), u2 = csub(s0, s2);
    float2 u1 = cadd(s1, s3), u3t = csub(s1, s3);
    float2 u3 = make_float2(-(float)S * u3t.y, (float)S * u3t.x);
    v[0] = cadd(u0, u1); v[1] = csub(u0, u1); v[2] = cadd(u2, u3); v[3] = csub(u2, u3);
    float2 w0 = cadd(d0, d2), w2 = csub(d0, d2);
    float2 w1 = cadd(d1, d3), w3t = csub(d1, d3);
    float2 w3 = make_float2(-(float)S * w3t.y, (float)S * w3t.x);
    v[4] = cadd(w0, w1); v[5] = csub(w0, w1); v[6] = cadd(w2, w3); v[7] = csub(w2, w3);
}

template <int S>
__device__ __forceinline__ void fft4(float2& a, float2& b, float2& c, float2& d) {
    float2 t0 = cadd(a, c), t1 = csub(a, c);
    float2 t2 = cadd(b, d), t3 = csub(b, d);
    a = cadd(t0, t2);
    c = csub(t0, t2);
    b = make_float2(t1.x - (float)S * t3.y, t1.y + (float)S * t3.x);
    d = make_float2(t1.x + (float)S * t3.y, t1.y - (float)S * t3.x);
}

// 16-pt FFT in registers, natural order in/out, radix 4x4.
template <int S>
__device__ __forceinline__ void fft16(float2 v[16]) {
    const float CS[10] = {1.f, 0.92387953f, 0.70710678f, 0.38268343f, 0.f,
                          -0.38268343f, -0.70710678f, -0.92387953f, -1.f, -0.92387953f};
    const float SN[10] = {0.f, 0.38268343f, 0.70710678f, 0.92387953f, 1.f,
                          0.92387953f, 0.70710678f, 0.38268343f, 0.f, -0.38268343f};
    float2 A[4][4];
#pragma unroll
    for (int j = 0; j < 4; ++j) {
        A[j][0] = v[j]; A[j][1] = v[4 + j]; A[j][2] = v[8 + j]; A[j][3] = v[12 + j];
        fft4<S>(A[j][0], A[j][1], A[j][2], A[j][3]);
#pragma unroll
        for (int k0 = 0; k0 < 4; ++k0) {
            int m = j * k0;
            float2 tw = make_float2(CS[m], (float)S * SN[m]);
            A[j][k0] = cmul(A[j][k0], tw);
        }
    }
#pragma unroll
    for (int k0 = 0; k0 < 4; ++k0) {
        fft4<S>(A[0][k0], A[1][k0], A[2][k0], A[3][k0]);
        v[k0] = A[0][k0]; v[k0 + 4] = A[1][k0]; v[k0 + 8] = A[2][k0]; v[k0 + 12] = A[3][k0];
    }
}

// ---------------------------------------------------------------------------
// Radix-8x8 64-pt FFT along W, real fp32 input -> bf16 complex. wg per (b,t,h).
// Block 0 additionally builds the bf16 W-fragment table for k_mid's MFMA.
// ---------------------------------------------------------------------------
__global__ __launch_bounds__(256, 4) void k_fft_w_fwd(const float* __restrict__ x,
                                                      unsigned* __restrict__ X,
                                                      const float* __restrict__ dW,
                                                      unsigned* __restrict__ pre) {
    __shared__ unsigned ex[64 * 65];   // bf16-packed transpose buffer, 16.6 KB
    const int brev[8] = {0, 4, 2, 6, 1, 5, 3, 7};
    int tid = threadIdx.x;

    if (blockIdx.x == 0) {
        // pre[((nt*2+ka)*64 + lane)*4 + p2] = pack(W[kb][ccol], W[kb+1][ccol]),
        // kb = ka*32 + (lane>>4)*8 + 2*p2, ccol = (lane&15) + 16*nt
        for (int i = tid; i < 2048; i += 256) {
            int p2 = i & 3, lane = (i >> 2) & 63, ka = (i >> 8) & 1, nt = i >> 9;
            int kb = ka * 32 + (lane >> 4) * 8 + 2 * p2;
            int ccol = (lane & 15) + 16 * nt;
            pre[i] = bfpack(make_float2(dW[kb * 64 + ccol], dW[(kb + 1) * 64 + ccol]));
        }
    }

    int j = tid >> 5, cl = tid & 31;
    int base = blockIdx.x * 4096;
    float2 v[2][8];
#pragma unroll
    for (int q = 0; q < 2; ++q) {
        int c = cl + 32 * q;
#pragma unroll
        for (int n1 = 0; n1 < 8; ++n1)
            v[q][n1] = make_float2(x[base + (8 * n1 + j) * 64 + c], 0.f);
    }
    float sj, cj; sincosf(-TWO_PI * (float)j / 64.f, &sj, &cj);
    float2 w1 = make_float2(cj, sj);
#pragma unroll
    for (int q = 0; q < 2; ++q) {
        fft8<-1>(v[q]);
        int c = cl + 32 * q;
        float2 tw = make_float2(1.f, 0.f);
#pragma unroll
        for (int k0 = 0; k0 < 8; ++k0) {
            ex[c * 65 + j * 8 + k0] = bfpack(cmul(v[q][brev[k0]], tw));
            tw = cmul(tw, w1);
        }
    }
    __syncthreads();
#pragma unroll
    for (int q = 0; q < 2; ++q) {
        int c = cl + 32 * q;
        float2 z[8];
#pragma unroll
        for (int n0 = 0; n0 < 8; ++n0) z[n0] = bfunpack(ex[c * 65 + n0 * 8 + j]);
        fft8<-1>(z);
#pragma unroll
        for (int m = 0; m < 8; ++m)
            X[base + (j + 8 * brev[m]) * 64 + c] = bfpack(z[m]);
    }
}

// ---------------------------------------------------------------------------
// Radix-8x8 64-pt FFT along H, bf16 complex in-place. wg per (b,t,w).
// ---------------------------------------------------------------------------
template <int S, int SHIFT>
__global__ __launch_bounds__(256, 4) void k_fft_h(unsigned* __restrict__ X) {
    __shared__ unsigned ex[64 * 65];
    const int brev[8] = {0, 4, 2, 6, 1, 5, 3, 7};
    const float sc = 1.0f / (float)(1 << SHIFT);
    int tid = threadIdx.x;
    int j = tid >> 5, cl = tid & 31;
    int s = blockIdx.x;
    int bt = s >> 6, w = s & 63;
    int base = bt * ST_ + w * 64;
    float2 v[2][8];
#pragma unroll
    for (int q = 0; q < 2; ++q) {
        int c = cl + 32 * q;
#pragma unroll
        for (int n1 = 0; n1 < 8; ++n1)
            v[q][n1] = bfunpack(X[base + (8 * n1 + j) * SH_ + c]);
    }
    float sj, cj; sincosf((float)S * TWO_PI * (float)j / 64.f, &sj, &cj);
    float2 w1 = make_float2(cj, sj);
#pragma unroll
    for (int q = 0; q < 2; ++q) {
        fft8<S>(v[q]);
        int c = cl + 32 * q;
        float2 tw = make_float2(1.f, 0.f);
#pragma unroll
        for (int k0 = 0; k0 < 8; ++k0) {
            ex[c * 65 + j * 8 + k0] = bfpack(cmul(v[q][brev[k0]], tw));
            tw = cmul(tw, w1);
        }
    }
    __syncthreads();
#pragma unroll
    for (int q = 0; q < 2; ++q) {
        int c = cl + 32 * q;
        float2 z[8];
#pragma unroll
        for (int n0 = 0; n0 < 8; ++n0) z[n0] = bfunpack(ex[c * 65 + n0 * 8 + j]);
        fft8<S>(z);
#pragma unroll
        for (int m = 0; m < 8; ++m) {
            float2 o = make_float2(z[m].x * sc, z[m].y * sc);
            X[base + (j + 8 * brev[m]) * SH_ + c] = bfpack(o);
        }
    }
}

// ---------------------------------------------------------------------------
// Fused: FFT-16 fwd along T + gates + MFMA delta-matmul + scan + FFT-16 inv.
// 256 thr = 4 waves = 4 sites (b,h,w); lane = channel c.
// B-fragments of delta_W come precomputed from `pre` (global, L2-resident).
// Output scaled by 1/16.
// ---------------------------------------------------------------------------
__global__ __launch_bounds__(256) void k_mid(
    const float* __restrict__ x, unsigned* __restrict__ X,
    const float* __restrict__ Ak, const float* __restrict__ Bk,
    const float* __restrict__ fb, const float* __restrict__ fs,
    const float* __restrict__ ib, const float* __restrict__ isc_,
    const uint4* __restrict__ pre, const float* __restrict__ db) {
    const float CT[16] = {1.f, 0.9238795f, 0.7071068f, 0.3826834f, 0.f, -0.3826834f,
                          -0.7071068f, -0.9238795f, -1.f, -0.9238795f, -0.7071068f,
                          -0.3826834f, 0.f, 0.3826834f, 0.7071068f, 0.9238795f};
    const float SN[16] = {0.f, 0.3826834f, 0.7071068f, 0.9238795f, 1.f, 0.9238795f,
                          0.7071068f, 0.3826834f, 0.f, -0.3826834f, -0.7071068f,
                          -0.9238795f, -1.f, -0.9238795f, -0.7071068f, -0.3826834f};
    __shared__ float Akl[1728], Bkl[1728];              // kernels staged, [c*27+off]
    __shared__ __align__(16) float xs[4][16 * 68 + 4];  // per-wave x rows; reused for delta

    int tid = threadIdx.x;
    int g = tid >> 6, lane = tid & 63;
    int c = lane;
    int site = blockIdx.x * 4 + g;
    int b = site >> 12, hw = site & 4095;
    int h = hw >> 6, w = hw & 63;
    int base = b * SB_ + hw * 64;

    for (int i = tid; i < 1728; i += 256) { Akl[i] = Ak[i]; Bkl[i] = Bk[i]; }

    // per-lane loads: x and X T-lines
    float xv[16];
    float2 v[16];
#pragma unroll
    for (int t = 0; t < 16; ++t) {
        xv[t] = x[base + t * ST_ + c];
        v[t] = bfunpack(X[base + t * ST_ + c]);
    }
#pragma unroll
    for (int t = 0; t < 16; ++t) xs[g][t * 68 + c] = xv[t];
    __syncthreads();

    // ---- MFMA delta matmul: D[t][ccol] = sum_d x[t][d] W[d][ccol] + db ----
    int m = lane & 15, q = lane >> 4;
    bf16x8 Afrag[2];
#pragma unroll
    for (int ka = 0; ka < 2; ++ka) {
        int d0 = ka * 32 + q * 8;
        const float* p = &xs[g][m * 68 + d0];
        float4 f0 = *(const float4*)p;
        float4 f1 = *(const float4*)(p + 4);
        union { bf16x8 v8; unsigned u[4]; } U;
        U.u[0] = bfpack(make_float2(f0.x, f0.y));
        U.u[1] = bfpack(make_float2(f0.z, f0.w));
        U.u[2] = bfpack(make_float2(f1.x, f1.y));
        U.u[3] = bfpack(make_float2(f1.z, f1.w));
        Afrag[ka] = U.v8;
    }
#pragma unroll
    for (int nt = 0; nt < 4; ++nt) {
        int ccol = m + 16 * nt;
        float dbn = db[ccol];
        f32x4 acc = {dbn, dbn, dbn, dbn};
#pragma unroll
        for (int ka = 0; ka < 2; ++ka) {
            union { bf16x8 v8; uint4 u4; } Ub;
            Ub.u4 = pre[(nt * 2 + ka) * 64 + lane];
            acc = __builtin_amdgcn_mfma_f32_16x16x32_bf16(Afrag[ka], Ub.v8, acc, 0, 0, 0);
        }
#pragma unroll
        for (int reg = 0; reg < 4; ++reg)
            xs[g][(q * 4 + reg) * 68 + ccol] = acc[reg];
    }

    // ---- A_f/B_f generators from the 27 taps ----
    float sh, ch; sincosf(TWO_PI * (float)h / 64.0f, &sh, &ch);
    float sw, cw; sincosf(TWO_PI * (float)w / 64.0f, &sw, &cw);
    float2 eh[3] = { make_float2(ch, sh), make_float2(1.f, 0.f), make_float2(ch, -sh) };
    float2 ew[3] = { make_float2(cw, sw), make_float2(1.f, 0.f), make_float2(cw, -sw) };
    float2 GA[3], GB[3];
#pragma unroll
    for (int kt = 0; kt < 3; ++kt) { GA[kt] = make_float2(0.f, 0.f); GB[kt] = make_float2(0.f, 0.f); }
#pragma unroll
    for (int kh = 0; kh < 3; ++kh) {
#pragma unroll
        for (int kw = 0; kw < 3; ++kw) {
            float2 e = cmul(eh[kh], ew[kw]);
#pragma unroll
            for (int kt = 0; kt < 3; ++kt) {
                float ka = Akl[c * 27 + kt * 9 + kh * 3 + kw];
                float kb = Bkl[c * 27 + kt * 9 + kh * 3 + kw];
                GA[kt].x = fmaf(ka, e.x, GA[kt].x);
                GA[kt].y = fmaf(ka, e.y, GA[kt].y);
                GB[kt].x = fmaf(kb, e.x, GB[kt].x);
                GB[kt].y = fmaf(kb, e.y, GB[kt].y);
            }
        }
    }
    float fbc = fb[c], fsc = fs[c], ibc = ib[c], iscv = isc_[c];

    fft16<-1>(v);
    __syncthreads();  // delta (in xs) visible / ordered

    float delta_raw[16];
#pragma unroll
    for (int t = 0; t < 16; ++t) delta_raw[t] = xs[g][t * 68 + c];

    float2 hv = make_float2(0.f, 0.f);
#pragma unroll
    for (int t = 0; t < 16; ++t) {
        float ct = CT[t], st = SN[t];
        float2 Af, Bf;
        Af.x = GA[1].x + ct * (GA[0].x + GA[2].x) - st * (GA[0].y - GA[2].y);
        Af.y = GA[1].y + ct * (GA[0].y + GA[2].y) + st * (GA[0].x - GA[2].x);
        Bf.x = GB[1].x + ct * (GB[0].x + GB[2].x) - st * (GB[0].y - GB[2].y);
        Bf.y = GB[1].y + ct * (GB[0].y + GB[2].y) + st * (GB[0].x - GB[2].x);

        float xc = xv[t];
        float fg  = __builtin_amdgcn_rcpf(1.f + __expf(-(fbc + fsc * xc)));
        float igv = __builtin_amdgcn_rcpf(1.f + __expf(-(ibc + iscv * xc)));
        float dot = delta_raw[t];
        float delta = (dot > 20.f) ? dot : __logf(1.f + __expf(dot));

        float sR = igv * delta;
        float2 bbv;
        bbv.x = sR * (Bf.x * v[t].x - Bf.y * v[t].y);
        bbv.y = sR * (Bf.x * v[t].y + Bf.y * v[t].x);
        float2 av = make_float2(fg * Af.x, fg * Af.y);
        float2 nh;
        nh.x = av.x * hv.x - av.y * hv.y + bbv.x;
        nh.y = av.x * hv.y + av.y * hv.x + bbv.y;
        hv = nh;
        v[t] = hv;
    }

    fft16<1>(v);

#pragma unroll
    for (int t = 0; t < 16; ++t) {
        float2 o = make_float2(v[t].x * 0.0625f, v[t].y * 0.0625f);
        X[base + t * ST_ + c] = bfpack(o);
    }
}

// ---------------------------------------------------------------------------
// Radix-8x8 inverse 64-pt FFT along W + real output * 1/64.
// ---------------------------------------------------------------------------
__global__ __launch_bounds__(256, 4) void k_fft_w_inv_out(const unsigned* __restrict__ X,
                                                          float* __restrict__ out) {
    __shared__ unsigned ex[64 * 65];
    const int brev[8] = {0, 4, 2, 6, 1, 5, 3, 7};
    int tid = threadIdx.x;
    int j = tid >> 5, cl = tid & 31;
    int base = blockIdx.x * 4096;
    float2 v[2][8];
#pragma unroll
    for (int q = 0; q < 2; ++q) {
        int c = cl + 32 * q;
#pragma unroll
        for (int n1 = 0; n1 < 8; ++n1)
            v[q][n1] = bfunpack(X[base + (8 * n1 + j) * 64 + c]);
    }
    float sj, cj; sincosf(TWO_PI * (float)j / 64.f, &sj, &cj);
    float2 w1 = make_float2(cj, sj);
#pragma unroll
    for (int q = 0; q < 2; ++q) {
        fft8<1>(v[q]);
        int c = cl + 32 * q;
        float2 tw = make_float2(1.f, 0.f);
#pragma unroll
        for (int k0 = 0; k0 < 8; ++k0) {
            ex[c * 65 + j * 8 + k0] = bfpack(cmul(v[q][brev[k0]], tw));
            tw = cmul(tw, w1);
        }
    }
    __syncthreads();
#pragma unroll
    for (int q = 0; q < 2; ++q) {
        int c = cl + 32 * q;
        float2 z[8];
#pragma unroll
        for (int n0 = 0; n0 < 8; ++n0) z[n0] = bfunpack(ex[c * 65 + n0 * 8 + j]);
        fft8<1>(z);
#pragma unroll
        for (int m = 0; m < 8; ++m)
            out[base + (j + 8 * brev[m]) * 64 + c] = z[m].x * (1.0f / 64.0f);
    }
}

extern "C" void kernel_launch(void* const* d_in, const int* in_sizes, int n_in,
                              void* d_out, int out_size, void* d_ws, size_t ws_size,
                              hipStream_t stream) {
    const float* x   = (const float*)d_in[0];
    const float* Ak  = (const float*)d_in[1];
    const float* Bk  = (const float*)d_in[2];
    const float* fb  = (const float*)d_in[3];
    const float* fs  = (const float*)d_in[4];
    const float* ib  = (const float*)d_in[5];
    const float* is_ = (const float*)d_in[6];
    const float* dW  = (const float*)d_in[7];
    const float* db  = (const float*)d_in[8];
    float* out = (float*)d_out;
    unsigned* X = (unsigned*)d_ws;                       // bf16 complex pairs, 33.5 MB
    unsigned* pre = (unsigned*)((char*)d_ws + (size_t)XELEMS * 4);  // 8 KB W-frag table

    k_fft_w_fwd<<<Bb * Tt * Hh, 256, 0, stream>>>(x, X, dW, pre);
    k_fft_h<-1, 0><<<Bb * Tt * Ww, 256, 0, stream>>>(X);
    k_mid<<<(Bb * Hh * Ww) / 4, 256, 0, stream>>>(x, X, Ak, Bk, fb, fs, ib, is_,
                                                  (const uint4*)pre, db);
    k_fft_h<1, 6><<<Bb * Tt * Ww, 256, 0, stream>>>(X);
    k_fft_w_inv_out<<<Bb * Tt * Hh, 256, 0, stream>>>(X, out);
}